// Round 4
// baseline (204.852 us; speedup 1.0000x reference)
//
#include <hip/hip_runtime.h>

// out[r,d] = x0[r,d] * dot(x_cross[r,:], w) + b[d] + x_cross[r,d]
// B=16384 rows, D=4096 cols, all fp32.
//
// R4: one WAVE per row (was: one 4-wave block per row).
//  - No __syncthreads, no LDS: reduction is 6x shfl_xor within the wave,
//    every lane ends with the full sum (broadcast free).
//  - Each wave is fully independent -> no cross-wave gating of stores.
//  - xc kept in registers (16 x float4 = 64 VGPR); epilogue streams x0
//    with unroll 4 to cap register pressure.
//  - Nontemporal stores for out (streaming, zero reuse).

typedef float f32x4 __attribute__((ext_vector_type(4)));

constexpr int D_DIM = 4096;
constexpr int TPB   = 256;            // 4 waves per block -> 4 rows per block
constexpr int ROWS_PER_BLOCK = TPB / 64;
constexpr int V4_ROW = D_DIM / 4;     // 1024 float4 per row
constexpr int F4PL   = V4_ROW / 64;   // 16 float4 per lane

__global__ __launch_bounds__(TPB)
void cross_fused_kernel(const float* __restrict__ x0,
                        const float* __restrict__ xc,
                        const float* __restrict__ w,
                        const float* __restrict__ bias,
                        float* __restrict__ out) {
    const int wid  = threadIdx.x >> 6;
    const int lane = threadIdx.x & 63;
    const int row  = blockIdx.x * ROWS_PER_BLOCK + wid;
    const size_t base = (size_t)row * D_DIM;

    const f32x4* __restrict__ xc4  = (const f32x4*)(xc + base);
    const f32x4* __restrict__ x04  = (const f32x4*)(x0 + base);
    const f32x4* __restrict__ w4   = (const f32x4*)w;
    const f32x4* __restrict__ b4   = (const f32x4*)bias;
    f32x4* __restrict__       out4 = (f32x4*)(out + base);

    // Phase 1: load the whole row of xc into registers (coalesced: lane-
    // contiguous float4 at idx = lane + 64*i), dot with w as it arrives.
    f32x4 xcv[F4PL];
#pragma unroll
    for (int i = 0; i < F4PL; ++i)
        xcv[i] = xc4[lane + 64 * i];

    float p0 = 0.f, p1 = 0.f, p2 = 0.f, p3 = 0.f;
#pragma unroll
    for (int i = 0; i < F4PL; ++i) {
        const f32x4 wv = w4[lane + 64 * i];   // 16 KiB, L2-resident
        p0 += xcv[i].x * wv.x;
        p1 += xcv[i].y * wv.y;
        p2 += xcv[i].z * wv.z;
        p3 += xcv[i].w * wv.w;
    }
    float partial = (p0 + p1) + (p2 + p3);

    // Wave-64 butterfly reduction: all lanes end with the full row sum.
#pragma unroll
    for (int off = 32; off >= 1; off >>= 1)
        partial += __shfl_xor(partial, off);
    const float s = partial;

    // Phase 2: stream x0 -> out. unroll 4 keeps ~4 loads in flight per lane
    // without blowing up VGPR count; waves are independent so TLP covers
    // the rest of the latency.
#pragma unroll 4
    for (int i = 0; i < F4PL; ++i) {
        const int idx = lane + 64 * i;
        const f32x4 x0v = x04[idx];
        const f32x4 bv  = b4[idx];            // 16 KiB, L2-resident
        f32x4 o;
        o.x = fmaf(x0v.x, s, bv.x + xcv[i].x);
        o.y = fmaf(x0v.y, s, bv.y + xcv[i].y);
        o.z = fmaf(x0v.z, s, bv.z + xcv[i].z);
        o.w = fmaf(x0v.w, s, bv.w + xcv[i].w);
        __builtin_nontemporal_store(o, &out4[idx]);
    }
}

extern "C" void kernel_launch(void* const* d_in, const int* in_sizes, int n_in,
                              void* d_out, int out_size, void* d_ws, size_t ws_size,
                              hipStream_t stream) {
    const float* x0   = (const float*)d_in[0];
    const float* xc   = (const float*)d_in[1];
    const float* w    = (const float*)d_in[2];
    const float* bias = (const float*)d_in[3];
    float* out        = (float*)d_out;

    const int rows = in_sizes[0] / D_DIM;     // 16384
    cross_fused_kernel<<<rows / ROWS_PER_BLOCK, TPB, 0, stream>>>(x0, xc, w, bias, out);
}

// Round 5
// 159.061 us; speedup vs baseline: 1.2879x; 1.2879x over previous
//
#include <hip/hip_runtime.h>

// out[r,d] = x0[r,d] * dot(x_cross[r,:], w) + b[d] + x_cross[r,d]
// B=16384 rows, D=4096 cols, all fp32. Min HBM traffic 512 MiB/replay
// (256 MiB of the 512 MiB input reads are L3-resident; writes stream).
//
// R5: persistent pipelined block (NR=8 rows/block, block-per-row layout kept).
//  - Two-deep software pipeline with NAMED A/B register sets: loads of row
//    r+1 are in flight while row r stores + row r+1 reduce run.
//  - w and b loaded ONCE per block into registers (same per-thread columns
//    for every row) -> 8 fewer L2-hit VMEM per thread per row.
//  - Double-buffered LDS reduce slots so consecutive reduces don't race.
//  - Nontemporal stores (streaming output, keep L3 for inputs).

typedef float f32x4 __attribute__((ext_vector_type(4)));

constexpr int D_DIM = 4096;
constexpr int TPB   = 256;          // 4 waves per block
constexpr int V4    = D_DIM / 4;    // 1024 float4 per row
constexpr int F4PT  = V4 / TPB;     // 4 float4 per thread per row
constexpr int NR    = 8;            // rows per block

#define LOADROW(XCV, X0V, R)                                                  \
    {                                                                         \
        const f32x4* __restrict__ xc4_ = (const f32x4*)(xc + (R) * D_DIM);    \
        const f32x4* __restrict__ x04_ = (const f32x4*)(x0 + (R) * D_DIM);    \
        _Pragma("unroll")                                                     \
        for (int i = 0; i < F4PT; ++i) XCV[i] = xc4_[t + i * TPB];            \
        _Pragma("unroll")                                                     \
        for (int i = 0; i < F4PT; ++i) X0V[i] = x04_[t + i * TPB];            \
    }

#define REDUCE(XCV, SLOT, SOUT)                                               \
    {                                                                         \
        float p0 = 0.f, p1 = 0.f, p2 = 0.f, p3 = 0.f;                         \
        _Pragma("unroll")                                                     \
        for (int i = 0; i < F4PT; ++i) {                                      \
            p0 += XCV[i].x * wv[i].x;                                         \
            p1 += XCV[i].y * wv[i].y;                                         \
            p2 += XCV[i].z * wv[i].z;                                         \
            p3 += XCV[i].w * wv[i].w;                                         \
        }                                                                     \
        float partial_ = (p0 + p1) + (p2 + p3);                               \
        _Pragma("unroll")                                                     \
        for (int off = 32; off >= 1; off >>= 1)                               \
            partial_ += __shfl_xor(partial_, off);                            \
        if (lane == 0) wsum[SLOT][wid] = partial_;                            \
        __syncthreads();                                                      \
        SOUT = wsum[SLOT][0] + wsum[SLOT][1] + wsum[SLOT][2] + wsum[SLOT][3]; \
    }

#define STOREROW(XCV, X0V, S, R)                                              \
    {                                                                         \
        f32x4* __restrict__ out4_ = (f32x4*)(out + (R) * D_DIM);              \
        _Pragma("unroll")                                                     \
        for (int i = 0; i < F4PT; ++i) {                                      \
            f32x4 o_;                                                         \
            o_.x = fmaf(X0V[i].x, (S), bv[i].x + XCV[i].x);                   \
            o_.y = fmaf(X0V[i].y, (S), bv[i].y + XCV[i].y);                   \
            o_.z = fmaf(X0V[i].z, (S), bv[i].z + XCV[i].z);                   \
            o_.w = fmaf(X0V[i].w, (S), bv[i].w + XCV[i].w);                   \
            __builtin_nontemporal_store(o_, &out4_[t + i * TPB]);             \
        }                                                                     \
    }

__global__ __launch_bounds__(TPB)
void cross_fused_kernel(const float* __restrict__ x0,
                        const float* __restrict__ xc,
                        const float* __restrict__ w,
                        const float* __restrict__ bias,
                        float* __restrict__ out) {
    const int t    = threadIdx.x;
    const int lane = t & 63;
    const int wid  = t >> 6;
    const size_t row0 = (size_t)blockIdx.x * NR;

    const f32x4* __restrict__ w4 = (const f32x4*)w;
    const f32x4* __restrict__ b4 = (const f32x4*)bias;

    // w/b columns are identical for every row this thread touches: load once.
    f32x4 wv[F4PT], bv[F4PT];
#pragma unroll
    for (int i = 0; i < F4PT; ++i) {
        wv[i] = w4[t + i * TPB];
        bv[i] = b4[t + i * TPB];
    }

    __shared__ float wsum[2][TPB / 64];

    f32x4 xcA[F4PT], x0A[F4PT], xcB[F4PT], x0B[F4PT];
    float sA, sB;

    // Prologue: row 0 into set A, reduce.
    LOADROW(xcA, x0A, row0);
    REDUCE(xcA, 0, sA);

#pragma unroll
    for (int r = 0; r < NR; r += 2) {
        // Loads of row r+1 go in flight BEFORE row r's stores.
        LOADROW(xcB, x0B, row0 + r + 1);
        STOREROW(xcA, x0A, sA, row0 + r);
        REDUCE(xcB, 1, sB);
        if (r + 2 < NR) LOADROW(xcA, x0A, row0 + r + 2);
        STOREROW(xcB, x0B, sB, row0 + r + 1);
        if (r + 2 < NR) REDUCE(xcA, 0, sA);
    }
}

extern "C" void kernel_launch(void* const* d_in, const int* in_sizes, int n_in,
                              void* d_out, int out_size, void* d_ws, size_t ws_size,
                              hipStream_t stream) {
    const float* x0   = (const float*)d_in[0];
    const float* xc   = (const float*)d_in[1];
    const float* w    = (const float*)d_in[2];
    const float* bias = (const float*)d_in[3];
    float* out        = (float*)d_out;

    const int rows = in_sizes[0] / D_DIM;     // 16384
    cross_fused_kernel<<<rows / NR, TPB, 0, stream>>>(x0, xc, w, bias, out);
}